// Round 9
// baseline (366.987 us; speedup 1.0000x reference)
//
#include <hip/hip_runtime.h>
#include <hip/hip_bf16.h>

// Problem sizes (fixed)
#define B_    8
#define C_    256
#define NPIX  16384           // 128*128
#define KCG   32              // K-chunks for gram
#define KCHG  (NPIX / KCG)    // 512 px per chunk
#define GSTEP 32              // K per LDS step
#define NSTEPG (KCHG / GSTEP) // 16 steps

typedef __attribute__((ext_vector_type(8))) short bf16x8;
typedef __attribute__((ext_vector_type(4))) float f32x4;
typedef unsigned int uint_;

__device__ __forceinline__ unsigned short f2bf(float x) {
  unsigned int u = __builtin_bit_cast(unsigned int, x);
  u = (u + 0x7fffu + ((u >> 16) & 1u)) >> 16;   // RTNE
  return (unsigned short)u;
}
__device__ __forceinline__ float fcomp(const float4& v, int i) {
  switch (i) { case 0: return v.x; case 1: return v.y; case 2: return v.z; default: return v.w; }
}
// swizzled index into a [rows][32]-short LDS tile (16B-unit XOR)
__device__ __forceinline__ int swz32(int row, int col) {
  return row * 32 + ((((col >> 3) ^ (row >> 1)) & 3) << 3) + (col & 7);
}

// ---------------- k_gram: quadrant partials of P = H*(H/2 + L)^T ------------
// G = P + P^T == HH^T + HL^T + LH^T. grid 1024 = chunk * 4 + q.
// 256 thr / 4 waves (2x2 of 64x64). LDS DOUBLE-buffered (48 KB, 3 blocks/CU),
// register prefetch of next step's loads, ONE barrier per step.
__global__ __launch_bounds__(256, 3) void k_gram(const float* __restrict__ x,
                                                 float* __restrict__ gpart,
                                                 float* __restrict__ spart) {
  const int bid = blockIdx.x;
  const int q   = bid & 3;
  const int t   = bid >> 2;
  const int kc  = t & (KCG - 1);
  const int b   = t >> 5;
  const int qi  = q >> 1, qj = q & 1;

  const float* Xa  = x + (size_t)b * C_ * NPIX + (size_t)(qi * 128) * NPIX + kc * KCHG;
  const float* Xb_ = x + (size_t)b * C_ * NPIX + (size_t)(qj * 128) * NPIX + kc * KCHG;

  __shared__ __align__(16) unsigned short AHi[2][128 * 32];  // 2 x 8 KB
  __shared__ __align__(16) unsigned short BHh[2][128 * 32];  // 2 x 8 KB (hi/2)
  __shared__ __align__(16) unsigned short BL [2][128 * 32];  // 2 x 8 KB (lo)

  const int tid  = threadIdx.x;
  const int lane = tid & 63;
  const int w    = tid >> 6;
  const int wr   = w >> 1, wc = w & 1;

  const int lrow = tid >> 3;          // 0..31
  const int lcol = (tid & 7) * 4;     // 0..28 (floats)

  f32x4 acc[4][4] = {};
  float rs[4] = {};
  float4 ga[4], gb[4];

#define GLOAD(ks)                                                             \
  _Pragma("unroll")                                                           \
  for (int j = 0; j < 4; ++j) {                                               \
    ga[j] = *reinterpret_cast<const float4*>(                                 \
        Xa + (size_t)(j * 32 + lrow) * NPIX + (ks) * GSTEP + lcol);           \
    gb[j] = *reinterpret_cast<const float4*>(                                 \
        Xb_ + (size_t)(j * 32 + lrow) * NPIX + (ks) * GSTEP + lcol);          \
  }

#define STAGE(buf)                                                            \
  _Pragma("unroll")                                                           \
  for (int j = 0; j < 4; ++j) {                                               \
    const int row = j * 32 + lrow;                                            \
    const int idx = swz32(row, lcol);                                         \
    const float4 va = ga[j];                                                  \
    rs[j] += (va.x + va.y) + (va.z + va.w);                                   \
    ushort4 ah;                                                               \
    ah.x = (unsigned short)(__builtin_bit_cast(uint_, va.x) >> 16);           \
    ah.y = (unsigned short)(__builtin_bit_cast(uint_, va.y) >> 16);           \
    ah.z = (unsigned short)(__builtin_bit_cast(uint_, va.z) >> 16);           \
    ah.w = (unsigned short)(__builtin_bit_cast(uint_, va.w) >> 16);           \
    *reinterpret_cast<ushort4*>(&AHi[buf][idx]) = ah;                         \
    const float4 vb = gb[j];                                                  \
    ushort4 bh, bl;                                                           \
    _Pragma("unroll")                                                         \
    for (int e = 0; e < 4; ++e) {                                             \
      const float xe = fcomp(vb, e);                                          \
      const uint_ ue = __builtin_bit_cast(uint_, xe);                         \
      const float hf = __builtin_bit_cast(float, ue & 0xffff0000u);           \
      const uint_ hh = __builtin_bit_cast(uint_, hf * 0.5f) >> 16;            \
      const uint_ lo = __builtin_bit_cast(uint_, xe - hf) >> 16;              \
      ((unsigned short*)&bh)[e] = (unsigned short)hh;                         \
      ((unsigned short*)&bl)[e] = (unsigned short)lo;                         \
    }                                                                         \
    *reinterpret_cast<ushort4*>(&BHh[buf][idx]) = bh;                         \
    *reinterpret_cast<ushort4*>(&BL [buf][idx]) = bl;                         \
  }

  GLOAD(0)
  STAGE(0)
  __syncthreads();

  for (int ks = 0; ks < NSTEPG; ++ks) {
    const int cur = ks & 1;
    if (ks + 1 < NSTEPG) GLOAD(ks + 1)   // in flight under MFMA phase
    // ---- MFMA phase on buf[cur]: 12 ds_read_b128, 32 MFMA ----
    const int kboff = (lane >> 4) * 8;
    __builtin_amdgcn_s_setprio(1);
    bf16x8 ahi[4];
#pragma unroll
    for (int m = 0; m < 4; ++m) {
      const int row = wr * 64 + m * 16 + (lane & 15);
      ahi[m] = *reinterpret_cast<const bf16x8*>(&AHi[cur][swz32(row, kboff)]);
    }
#pragma unroll
    for (int n = 0; n < 4; ++n) {
      const int row = wc * 64 + n * 16 + (lane & 15);
      bf16x8 bh = *reinterpret_cast<const bf16x8*>(&BHh[cur][swz32(row, kboff)]);
      bf16x8 bl = *reinterpret_cast<const bf16x8*>(&BL [cur][swz32(row, kboff)]);
#pragma unroll
      for (int m = 0; m < 4; ++m) {
        acc[m][n] = __builtin_amdgcn_mfma_f32_16x16x32_bf16(ahi[m], bh, acc[m][n], 0, 0, 0);
        acc[m][n] = __builtin_amdgcn_mfma_f32_16x16x32_bf16(ahi[m], bl, acc[m][n], 0, 0, 0);
      }
    }
    __builtin_amdgcn_s_setprio(0);
    // ---- convert + stage next step into the other buffer ----
    if (ks + 1 < NSTEPG) STAGE(cur ^ 1)
    __syncthreads();
  }
#undef GLOAD
#undef STAGE

  // rowsum partials (A region rows; qj==0 blocks cover every row once)
#pragma unroll
  for (int j = 0; j < 4; ++j) {
    rs[j] += __shfl_xor(rs[j], 1, 64);
    rs[j] += __shfl_xor(rs[j], 2, 64);
    rs[j] += __shfl_xor(rs[j], 4, 64);
  }
  if (qj == 0 && (tid & 7) == 0) {
#pragma unroll
    for (int j = 0; j < 4; ++j)
      spart[((size_t)b * KCG + kc) * 256 + qi * 128 + j * 32 + lrow] = rs[j];
  }

  // store P quadrant partial (128x128 f32, coalesced)
  float* gp = gpart + (size_t)bid * (128 * 128);
#pragma unroll
  for (int m = 0; m < 4; ++m) {
    const int row0 = wr * 64 + m * 16 + ((lane >> 4) << 2);
#pragma unroll
    for (int n = 0; n < 4; ++n) {
      const int col = wc * 64 + n * 16 + (lane & 15);
#pragma unroll
      for (int j = 0; j < 4; ++j)
        gp[(size_t)(row0 + j) * 128 + col] = acc[m][n][j];
    }
  }
}

// ------- k_reduce: G' = sum_kc P quadrants; also scatter G'^T (L2 WB) ------
__global__ __launch_bounds__(256) void k_reduce(const float* __restrict__ gpart,
                                                float* __restrict__ G,
                                                float* __restrict__ GT) {
  const int t  = blockIdx.x * 256 + threadIdx.x;   // 0..131071
  const int b  = t >> 14;
  const int i  = (t >> 6) & 255;
  const int j0 = (t & 63) * 4;
  const int qi = i >> 7, qj = j0 >> 7;
  const int il = i & 127, jl = j0 & 127;
  float4 s = make_float4(0.f, 0.f, 0.f, 0.f);
#pragma unroll
  for (int kc = 0; kc < KCG; ++kc) {
    const int bid = (((b * KCG + kc) << 2) | (qi << 1) | qj);
    const float4 v = *reinterpret_cast<const float4*>(
        &gpart[(size_t)bid * (128 * 128) + (size_t)il * 128 + jl]);
    s.x += v.x; s.y += v.y; s.z += v.z; s.w += v.w;
  }
  const size_t gb = (size_t)b * 65536;
  *reinterpret_cast<float4*>(&G[gb + (size_t)i * 256 + j0]) = s;
  GT[gb + (size_t)(j0 + 0) * 256 + i] = s.x;   // scattered 4B stores: L2
  GT[gb + (size_t)(j0 + 1) * 256 + i] = s.y;   // write-back combines them
  GT[gb + (size_t)(j0 + 2) * 256 + i] = s.z;
  GT[gb + (size_t)(j0 + 3) * 256 + i] = s.w;
}

// ---------------- k_transpose: 256x256 (w2 -> w2t) ----------------
__global__ __launch_bounds__(256) void k_transpose(const float* __restrict__ in,
                                                   float* __restrict__ outp) {
  __shared__ float t[32][33];
  const int bx = blockIdx.x & 7, by = blockIdx.x >> 3;
  const int tx = threadIdx.x & 31, ty = threadIdx.x >> 5;
#pragma unroll
  for (int i = 0; i < 32; i += 8)
    t[ty + i][tx] = in[(size_t)(by * 32 + ty + i) * 256 + bx * 32 + tx];
  __syncthreads();
#pragma unroll
  for (int i = 0; i < 32; i += 8)
    outp[(size_t)(bx * 32 + ty + i) * 256 + by * 32 + tx] = t[tx][ty + i];
}

// ---------------- k_u: s = reduce(spart); u1 = W1 s, u2 = W2 s --------------
__global__ __launch_bounds__(256) void k_u(const float* __restrict__ w1,
                                           const float* __restrict__ w2,
                                           const float* __restrict__ spart,
                                           float* __restrict__ u1,
                                           float* __restrict__ u2) {
  const int b = blockIdx.x;
  const int tid = threadIdx.x;
  __shared__ float sl[256];
  float sv = 0.f;
#pragma unroll
  for (int kc = 0; kc < KCG; ++kc) sv += spart[((size_t)b * KCG + kc) * 256 + tid];
  sl[tid] = sv;
  __syncthreads();
  float a1 = 0.f, a2 = 0.f;
#pragma unroll 4
  for (int c = 0; c < 256; ++c) {
    a1 += w1[(size_t)tid * 256 + c] * sl[c];
    a2 += w2[(size_t)tid * 256 + c] * sl[c];
  }
  u1[b * 256 + tid] = a1;
  u2[b * 256 + tid] = a2;
}

// -------- k_smallmm_dual: T1 = W1 @ (G' + G'^T) ----------
__global__ __launch_bounds__(256) void k_smallmm_dual(const float* __restrict__ A,
                                                      const float* __restrict__ B1,
                                                      const float* __restrict__ B2,
                                                      float* __restrict__ Cm) {
  const int b  = blockIdx.y;
  const int i0 = blockIdx.x * 8;
  const float* Bb1 = B1 + (size_t)65536 * b;
  const float* Bb2 = B2 + (size_t)65536 * b;
  float*       Cb  = Cm + (size_t)65536 * b;
  const int tid = threadIdx.x;
  __shared__ float arows[8][256];
#pragma unroll
  for (int rr = 0; rr < 8; ++rr) arows[rr][tid] = A[(size_t)(i0 + rr) * 256 + tid];
  __syncthreads();
  float acc[8] = {};
#pragma unroll 4
  for (int k = 0; k < 256; ++k) {
    const float bv = Bb1[(size_t)k * 256 + tid] + Bb2[(size_t)k * 256 + tid];
#pragma unroll
    for (int rr = 0; rr < 8; ++rr) acc[rr] += arows[rr][k] * bv;
  }
#pragma unroll
  for (int rr = 0; rr < 8; ++rr) Cb[(size_t)(i0 + rr) * 256 + tid] = acc[rr];
}

// ------- k_mm2sm: L = T1 @ w2t, + bias terms, row softmax, +I, -> Abf -------
// Each block owns 8 COMPLETE rows of L -> softmax fused in-block.
__global__ __launch_bounds__(256) void k_mm2sm(const float* __restrict__ T1,
                                               const float* __restrict__ w2t,
                                               const float* __restrict__ b1,
                                               const float* __restrict__ b2,
                                               const float* __restrict__ u1,
                                               const float* __restrict__ u2,
                                               unsigned short* __restrict__ Abf) {
  const int b  = blockIdx.y;
  const int i0 = blockIdx.x * 8;
  const float* Ab = T1 + (size_t)65536 * b;
  const int tid = threadIdx.x;
  const int lane = tid & 63, wv = tid >> 6;
  __shared__ float arows[8][256];
  __shared__ float redm[8][4], reds[8][4];
#pragma unroll
  for (int rr = 0; rr < 8; ++rr) arows[rr][tid] = Ab[(size_t)(i0 + rr) * 256 + tid];
  __syncthreads();
  float acc[8] = {};
#pragma unroll 4
  for (int k = 0; k < 256; ++k) {
    const float bv = w2t[(size_t)k * 256 + tid];
#pragma unroll
    for (int rr = 0; rr < 8; ++rr) acc[rr] += arows[rr][k] * bv;
  }
  // logits finish
  const float b2j = b2[tid];
  const float t2j = u2[b * 256 + tid] + 16384.f * b2j;
  float v[8];
#pragma unroll
  for (int rr = 0; rr < 8; ++rr)
    v[rr] = acc[rr] + u1[b * 256 + i0 + rr] * b2j + b1[i0 + rr] * t2j;
  // row max (wave shfl + LDS combine)
#pragma unroll
  for (int rr = 0; rr < 8; ++rr) {
    float m = v[rr];
#pragma unroll
    for (int off = 32; off; off >>= 1) m = fmaxf(m, __shfl_xor(m, off, 64));
    if (lane == 0) redm[rr][wv] = m;
  }
  __syncthreads();
  float e[8];
#pragma unroll
  for (int rr = 0; rr < 8; ++rr) {
    const float m = fmaxf(fmaxf(redm[rr][0], redm[rr][1]),
                          fmaxf(redm[rr][2], redm[rr][3]));
    e[rr] = __expf(v[rr] - m);
    float s = e[rr];
#pragma unroll
    for (int off = 32; off; off >>= 1) s += __shfl_xor(s, off, 64);
    if (lane == 0) reds[rr][wv] = s;
  }
  __syncthreads();
  const size_t base = ((size_t)b * 256 + i0) * 256;
#pragma unroll
  for (int rr = 0; rr < 8; ++rr) {
    const float sm = (reds[rr][0] + reds[rr][1]) + (reds[rr][2] + reds[rr][3]);
    float p = e[rr] / sm;
    if (tid == i0 + rr) p += 1.0f;      // residual folded into diagonal
    Abf[base + (size_t)rr * 256 + tid] = f2bf(p);
  }
}

// ------ k_av: out = (I+A) @ X, 4 px-tiles/block, T14 pipelined, dbuf --------
// grid 1024 = pxgroup(128) x b(8, low bits -> XCD-pinned); 256 thr / 4 waves.
// Per tile (32 px x 256 ch): next tile's X loads issued before this tile's
// MFMA; Xt double-buffered (2 x 16 KB); pure-store epilogue (no x re-read).
__global__ __launch_bounds__(256, 4) void k_av(const unsigned short* __restrict__ Abf,
                                               const float* __restrict__ x,
                                               float* __restrict__ out) {
  const int bid = blockIdx.x;
  const int b = bid & 7;
  const int pxbase = (bid >> 3) * 128;
  const unsigned short* Ab = Abf + (size_t)b * 65536;
  const float* Xb = x + (size_t)b * C_ * NPIX;
  float* Ob = out + (size_t)b * C_ * NPIX;

  __shared__ __align__(16) unsigned short Xt[2][32 * 256];   // 2 x 16 KB

  const int tid = threadIdx.x;
  const int lane = tid & 63, w = tid >> 6;   // w = ch-block 0..3
  const int pq = (tid & 7) * 4;
  const int dq = (tid >> 3) * 4;
  const float* xsb = Xb + (size_t)dq * NPIX + pxbase + pq;
  const int kboff = (lane >> 4) * 8;

  float4 gld[8];

#define GLD(t)                                                                \
  _Pragma("unroll")                                                           \
  for (int h = 0; h < 2; ++h)                                                 \
    _Pragma("unroll")                                                         \
    for (int r = 0; r < 4; ++r)                                               \
      gld[h * 4 + r] = *reinterpret_cast<const float4*>(                      \
          xsb + (size_t)(h * 128 + r) * NPIX + (t) * 32);

#define CONV(buf)                                                             \
  _Pragma("unroll")                                                           \
  for (int h = 0; h < 2; ++h) {                                               \
    const int d = dq + h * 128;                                               \
    _Pragma("unroll")                                                         \
    for (int i = 0; i < 4; ++i) {                                             \
      const int px = pq + i;                                                  \
      ushort4 v = make_ushort4(f2bf(fcomp(gld[h * 4 + 0], i)),                \
                               f2bf(fcomp(gld[h * 4 + 1], i)),                \
                               f2bf(fcomp(gld[h * 4 + 2], i)),                \
                               f2bf(fcomp(gld[h * 4 + 3], i)));               \
      const int idx = (px * 256 + d) ^ (((px ^ (px >> 2)) & 7) << 3);         \
      *reinterpret_cast<ushort4*>(&Xt[buf][idx]) = v;                         \
    }                                                                         \
  }

#define LOADA(kk, af)                                                         \
  _Pragma("unroll")                                                           \
  for (int m = 0; m < 4; ++m)                                                 \
    af[m] = *reinterpret_cast<const bf16x8*>(                                 \
        Ab + (size_t)(w * 64 + m * 16 + (lane & 15)) * 256 + (kk) * 32 + kboff);

#define LOADB(kk, buf)                                                        \
  _Pragma("unroll")                                                           \
  for (int n = 0; n < 2; ++n) {                                               \
    const int px = n * 16 + (lane & 15);                                      \
    bq[n] = *reinterpret_cast<const bf16x8*>(                                 \
        &Xt[buf][(px * 256 + (kk) * 32 + kboff) ^ (((px ^ (px >> 2)) & 7) << 3)]); \
  }

#define MFMA8(af)                                                             \
  _Pragma("unroll")                                                           \
  for (int m = 0; m < 4; ++m)                                                 \
    _Pragma("unroll")                                                         \
    for (int n = 0; n < 2; ++n)                                               \
      acc[m][n] = __builtin_amdgcn_mfma_f32_16x16x32_bf16(bq[n], af[m], acc[m][n], 0, 0, 0);

  GLD(0)
#pragma unroll
  for (int t = 0; t < 4; ++t) {
    const int buf = t & 1;
    CONV(buf)
    __syncthreads();

    bf16x8 afA[4], afB[4], bq[2];
    LOADA(0, afA)
    if (t < 3) GLD(t + 1)          // T14: next tile's HBM loads in flight

    f32x4 acc[4][2] = {};
    __builtin_amdgcn_s_setprio(1);
#pragma unroll
    for (int kk = 0; kk < 8; ++kk) {
      LOADB(kk, buf)
      if (kk < 7) {
        if (kk & 1) { LOADA(kk + 1, afA) } else { LOADA(kk + 1, afB) }
      }
      if (kk & 1) { MFMA8(afB) } else { MFMA8(afA) }
    }
    __builtin_amdgcn_s_setprio(0);

    // epilogue: pure float4 stores
#pragma unroll
    for (int m = 0; m < 4; ++m) {
      const int ch = w * 64 + m * 16 + (lane & 15);
      float* orow = Ob + (size_t)ch * NPIX + pxbase + t * 32;
#pragma unroll
      for (int n = 0; n < 2; ++n) {
        const int p0 = n * 16 + ((lane >> 4) << 2);
        *reinterpret_cast<float4*>(orow + p0) = *reinterpret_cast<const float4*>(&acc[m][n]);
      }
    }
  }
#undef GLD
#undef CONV
#undef LOADA
#undef LOADB
#undef MFMA8
}

extern "C" void kernel_launch(void* const* d_in, const int* in_sizes, int n_in,
                              void* d_out, int out_size, void* d_ws, size_t ws_size,
                              hipStream_t stream) {
  const float* x  = (const float*)d_in[0];
  const float* w1 = (const float*)d_in[1];
  const float* b1 = (const float*)d_in[2];
  const float* w2 = (const float*)d_in[3];
  const float* b2 = (const float*)d_in[4];
  float* out = (float*)d_out;
  char* ws = (char*)d_ws;

  // P-quadrant partials live in d_out (64 MB of its 134 MB) — consumed by
  // k_reduce before k_av overwrites d_out with the real output.
  float* gpart = out;

  constexpr size_t G_OFF     = 0;                                   // G'  2 MB
  constexpr size_t GT_OFF    = G_OFF   + (size_t)B_ * C_ * C_ * 4;  // G'T 2 MB
  constexpr size_t T1_OFF    = GT_OFF  + (size_t)B_ * C_ * C_ * 4;  // 2 MB
  constexpr size_t W2T_OFF   = T1_OFF  + (size_t)B_ * C_ * C_ * 4;  // 256 KB
  constexpr size_t SPART_OFF = W2T_OFF + (size_t)C_ * C_ * 4;       // 256 KB
  constexpr size_t U1_OFF    = SPART_OFF + (size_t)B_ * KCG * C_ * 4;
  constexpr size_t U2_OFF    = U1_OFF  + (size_t)B_ * C_ * 4;
  constexpr size_t ABF_OFF   = U2_OFF  + (size_t)B_ * C_ * 4;       // 1 MB

  float* G     = (float*)(ws + G_OFF);
  float* GT    = (float*)(ws + GT_OFF);
  float* T1    = (float*)(ws + T1_OFF);
  float* w2t   = (float*)(ws + W2T_OFF);
  float* spart = (float*)(ws + SPART_OFF);
  float* u1    = (float*)(ws + U1_OFF);
  float* u2    = (float*)(ws + U2_OFF);
  unsigned short* Abf = (unsigned short*)(ws + ABF_OFF);

  k_transpose   <<<64, 256, 0, stream>>>(w2, w2t);
  k_gram        <<<B_ * KCG * 4, 256, 0, stream>>>(x, gpart, spart);
  k_reduce      <<<512, 256, 0, stream>>>(gpart, G, GT);
  k_u           <<<B_, 256, 0, stream>>>(w1, w2, spart, u1, u2);
  k_smallmm_dual<<<dim3(32, B_), 256, 0, stream>>>(w1, G, GT, T1);
  k_mm2sm       <<<dim3(32, B_), 256, 0, stream>>>(T1, w2t, b1, b2, u1, u2, Abf);
  k_av          <<<1024, 256, 0, stream>>>(Abf, x, out);
}

// Round 10
// 259.225 us; speedup vs baseline: 1.4157x; 1.4157x over previous
//
#include <hip/hip_runtime.h>
#include <hip/hip_bf16.h>

// Problem sizes (fixed)
#define B_    8
#define C_    256
#define NPIX  16384           // 128*128
#define KCG   32              // K-chunks for gram
#define KCHG  (NPIX / KCG)    // 512 px per chunk
#define GSTEP 32              // K per LDS step
#define NSTEPG (KCHG / GSTEP) // 16 steps

typedef __attribute__((ext_vector_type(8))) short bf16x8;
typedef __attribute__((ext_vector_type(4))) float f32x4;
typedef unsigned int uint_;

__device__ __forceinline__ unsigned short f2bf(float x) {
  unsigned int u = __builtin_bit_cast(unsigned int, x);
  u = (u + 0x7fffu + ((u >> 16) & 1u)) >> 16;   // RTNE
  return (unsigned short)u;
}
__device__ __forceinline__ float fcomp(const float4& v, int i) {
  switch (i) { case 0: return v.x; case 1: return v.y; case 2: return v.z; default: return v.w; }
}
// swizzled index into a [rows][32]-short LDS tile (16B-unit XOR)
__device__ __forceinline__ int swz32(int row, int col) {
  return row * 32 + ((((col >> 3) ^ (row >> 1)) & 3) << 3) + (col & 7);
}

// ---------------- k_gram: quadrant partials of P = H*(H/2 + L)^T ------------
// G = P + P^T == HH^T + HL^T + LH^T. grid 1024: bid = q*256 + b*32 + kc so
// quadrant-mates are 256 apart -> same XCD. 256 thr / 4 waves (2x2 of 64x64).
// LDS double-buffered 48 KB -> 3 blocks/CU; reg prefetch; 1 barrier/step.
// If XBF: qj==0 blocks also emit Xbf = trunc-bf16(X) (k_av reads half bytes).
template<bool XBF>
__global__ __launch_bounds__(256) void k_gram(const float* __restrict__ x,
                                              float* __restrict__ gpart,
                                              float* __restrict__ spart,
                                              unsigned short* __restrict__ xbf) {
  const int bid = blockIdx.x;
  const int q   = bid >> 8;
  const int t   = bid & 255;
  const int kc  = t & (KCG - 1);
  const int b   = t >> 5;
  const int qi  = q >> 1, qj = q & 1;

  const float* Xa  = x + (size_t)b * C_ * NPIX + (size_t)(qi * 128) * NPIX + kc * KCHG;
  const float* Xb_ = x + (size_t)b * C_ * NPIX + (size_t)(qj * 128) * NPIX + kc * KCHG;

  __shared__ __align__(16) unsigned short AHi[2][128 * 32];  // 2 x 8 KB
  __shared__ __align__(16) unsigned short BHh[2][128 * 32];  // 2 x 8 KB (hi/2)
  __shared__ __align__(16) unsigned short BL [2][128 * 32];  // 2 x 8 KB (lo)

  const int tid  = threadIdx.x;
  const int lane = tid & 63;
  const int w    = tid >> 6;
  const int wr   = w >> 1, wc = w & 1;

  const int lrow = tid >> 3;          // 0..31
  const int lcol = (tid & 7) * 4;     // 0..28 (floats)

  f32x4 acc[4][4] = {};
  float rs[4] = {};
  float4 ga[4], gb[4];

#define GLOAD(ks)                                                             \
  _Pragma("unroll")                                                           \
  for (int j = 0; j < 4; ++j) {                                               \
    ga[j] = *reinterpret_cast<const float4*>(                                 \
        Xa + (size_t)(j * 32 + lrow) * NPIX + (ks) * GSTEP + lcol);           \
    gb[j] = *reinterpret_cast<const float4*>(                                 \
        Xb_ + (size_t)(j * 32 + lrow) * NPIX + (ks) * GSTEP + lcol);          \
  }

#define STAGE(buf, ksn)                                                       \
  _Pragma("unroll")                                                           \
  for (int j = 0; j < 4; ++j) {                                               \
    const int row = j * 32 + lrow;                                            \
    const int idx = swz32(row, lcol);                                         \
    const float4 va = ga[j];                                                  \
    rs[j] += (va.x + va.y) + (va.z + va.w);                                   \
    ushort4 ah;                                                               \
    ah.x = (unsigned short)(__builtin_bit_cast(uint_, va.x) >> 16);           \
    ah.y = (unsigned short)(__builtin_bit_cast(uint_, va.y) >> 16);           \
    ah.z = (unsigned short)(__builtin_bit_cast(uint_, va.z) >> 16);           \
    ah.w = (unsigned short)(__builtin_bit_cast(uint_, va.w) >> 16);           \
    *reinterpret_cast<ushort4*>(&AHi[buf][idx]) = ah;                         \
    if (XBF && qj == 0) {                                                     \
      *reinterpret_cast<ushort4*>(xbf + (size_t)b * C_ * NPIX +               \
          (size_t)(qi * 128 + row) * NPIX + kc * KCHG + (ksn) * GSTEP + lcol) = ah; \
    }                                                                         \
    const float4 vb = gb[j];                                                  \
    ushort4 bh, bl;                                                           \
    _Pragma("unroll")                                                         \
    for (int e = 0; e < 4; ++e) {                                             \
      const float xe = fcomp(vb, e);                                          \
      const uint_ ue = __builtin_bit_cast(uint_, xe);                         \
      const float hf = __builtin_bit_cast(float, ue & 0xffff0000u);           \
      const uint_ hh = __builtin_bit_cast(uint_, hf * 0.5f) >> 16;            \
      const uint_ lo = __builtin_bit_cast(uint_, xe - hf) >> 16;              \
      ((unsigned short*)&bh)[e] = (unsigned short)hh;                         \
      ((unsigned short*)&bl)[e] = (unsigned short)lo;                         \
    }                                                                         \
    *reinterpret_cast<ushort4*>(&BHh[buf][idx]) = bh;                         \
    *reinterpret_cast<ushort4*>(&BL [buf][idx]) = bl;                         \
  }

  GLOAD(0)
  STAGE(0, 0)
  __syncthreads();

  for (int ks = 0; ks < NSTEPG; ++ks) {
    const int cur = ks & 1;
    if (ks + 1 < NSTEPG) GLOAD(ks + 1)   // in flight under the MFMA phase
    const int kboff = (lane >> 4) * 8;
    __builtin_amdgcn_s_setprio(1);
    bf16x8 ahi[4];
#pragma unroll
    for (int m = 0; m < 4; ++m) {
      const int row = wr * 64 + m * 16 + (lane & 15);
      ahi[m] = *reinterpret_cast<const bf16x8*>(&AHi[cur][swz32(row, kboff)]);
    }
#pragma unroll
    for (int n = 0; n < 4; ++n) {
      const int row = wc * 64 + n * 16 + (lane & 15);
      bf16x8 bh = *reinterpret_cast<const bf16x8*>(&BHh[cur][swz32(row, kboff)]);
      bf16x8 bl = *reinterpret_cast<const bf16x8*>(&BL [cur][swz32(row, kboff)]);
#pragma unroll
      for (int m = 0; m < 4; ++m) {
        acc[m][n] = __builtin_amdgcn_mfma_f32_16x16x32_bf16(ahi[m], bh, acc[m][n], 0, 0, 0);
        acc[m][n] = __builtin_amdgcn_mfma_f32_16x16x32_bf16(ahi[m], bl, acc[m][n], 0, 0, 0);
      }
    }
    __builtin_amdgcn_s_setprio(0);
    if (ks + 1 < NSTEPG) STAGE(cur ^ 1, ks + 1)
    __syncthreads();
  }
#undef GLOAD
#undef STAGE

  // rowsum partials (A rows; qj==0 blocks cover each row once)
#pragma unroll
  for (int j = 0; j < 4; ++j) {
    rs[j] += __shfl_xor(rs[j], 1, 64);
    rs[j] += __shfl_xor(rs[j], 2, 64);
    rs[j] += __shfl_xor(rs[j], 4, 64);
  }
  if (qj == 0 && (tid & 7) == 0) {
#pragma unroll
    for (int j = 0; j < 4; ++j)
      spart[((size_t)b * KCG + kc) * 256 + qi * 128 + j * 32 + lrow] = rs[j];
  }

  // store P quadrant partial (128x128 f32, coalesced)
  float* gp = gpart + (size_t)bid * (128 * 128);
#pragma unroll
  for (int m = 0; m < 4; ++m) {
    const int row0 = wr * 64 + m * 16 + ((lane >> 4) << 2);
#pragma unroll
    for (int n = 0; n < 4; ++n) {
      const int col = wc * 64 + n * 16 + (lane & 15);
#pragma unroll
      for (int j = 0; j < 4; ++j)
        gp[(size_t)(row0 + j) * 128 + col] = acc[m][n][j];
    }
  }
}

// ------ k_reduce_sym: Gs = sum_kc P + (sum_kc P)^T, paired 32-tiles ---------
// grid (36 pairs, 8 b); both streams coalesced; transpose via LDS.
__global__ __launch_bounds__(256) void k_reduce_sym(const float* __restrict__ gpart,
                                                    float* __restrict__ Gs) {
  int p = blockIdx.x, it = 0;
  while (p >= 8 - it) { p -= 8 - it; ++it; }
  const int jt = it + p;
  const int b = blockIdx.y;
  const int t = threadIdx.x;
  const int r = t >> 3, c0 = (t & 7) * 4;

  const int qi2 = it >> 2, qj2 = jt >> 2;
  const int il  = (it & 3) * 32 + r;
  const int jl0 = (jt & 3) * 32 + c0;
  const int jlr = (jt & 3) * 32 + r;
  const int il0 = (it & 3) * 32 + c0;

  float4 aij = make_float4(0.f, 0.f, 0.f, 0.f);
  float4 aji = make_float4(0.f, 0.f, 0.f, 0.f);
#pragma unroll 4
  for (int kc = 0; kc < KCG; ++kc) {
    const size_t bij = ((size_t)((qi2 * 2 + qj2) * 256 + b * 32 + kc)) * 16384;
    const float4 v = *reinterpret_cast<const float4*>(&gpart[bij + (size_t)il * 128 + jl0]);
    aij.x += v.x; aij.y += v.y; aij.z += v.z; aij.w += v.w;
    const size_t bji = ((size_t)((qj2 * 2 + qi2) * 256 + b * 32 + kc)) * 16384;
    const float4 u = *reinterpret_cast<const float4*>(&gpart[bji + (size_t)jlr * 128 + il0]);
    aji.x += u.x; aji.y += u.y; aji.z += u.z; aji.w += u.w;
  }
  __shared__ float TA[32][33], TB[32][33];
  TA[r][c0 + 0] = aij.x; TA[r][c0 + 1] = aij.y; TA[r][c0 + 2] = aij.z; TA[r][c0 + 3] = aij.w;
  TB[r][c0 + 0] = aji.x; TB[r][c0 + 1] = aji.y; TB[r][c0 + 2] = aji.z; TB[r][c0 + 3] = aji.w;
  __syncthreads();
  float* Gb = Gs + (size_t)b * 65536;
  {
    float4 o = make_float4(aij.x + TB[c0 + 0][r], aij.y + TB[c0 + 1][r],
                           aij.z + TB[c0 + 2][r], aij.w + TB[c0 + 3][r]);
    *reinterpret_cast<float4*>(&Gb[(size_t)(it * 32 + r) * 256 + jt * 32 + c0]) = o;
  }
  if (it != jt) {
    float4 o = make_float4(aji.x + TA[c0 + 0][r], aji.y + TA[c0 + 1][r],
                           aji.z + TA[c0 + 2][r], aji.w + TA[c0 + 3][r]);
    *reinterpret_cast<float4*>(&Gb[(size_t)(jt * 32 + r) * 256 + it * 32 + c0]) = o;
  }
}

// ---------------- k_transpose: 256x256 (w2 -> w2t) ----------------
__global__ __launch_bounds__(256) void k_transpose(const float* __restrict__ in,
                                                   float* __restrict__ outp) {
  __shared__ float t[32][33];
  const int bx = blockIdx.x & 7, by = blockIdx.x >> 3;
  const int tx = threadIdx.x & 31, ty = threadIdx.x >> 5;
#pragma unroll
  for (int i = 0; i < 32; i += 8)
    t[ty + i][tx] = in[(size_t)(by * 32 + ty + i) * 256 + bx * 32 + tx];
  __syncthreads();
#pragma unroll
  for (int i = 0; i < 32; i += 8)
    outp[(size_t)(bx * 32 + ty + i) * 256 + by * 32 + tx] = t[tx][ty + i];
}

// ---------------- k_u: s = reduce(spart); u1 = W1 s, u2 = W2 s --------------
__global__ __launch_bounds__(256) void k_u(const float* __restrict__ w1,
                                           const float* __restrict__ w2,
                                           const float* __restrict__ spart,
                                           float* __restrict__ u1,
                                           float* __restrict__ u2) {
  const int b = blockIdx.x;
  const int tid = threadIdx.x;
  __shared__ float sl[256];
  float sv = 0.f;
#pragma unroll
  for (int kc = 0; kc < KCG; ++kc) sv += spart[((size_t)b * KCG + kc) * 256 + tid];
  sl[tid] = sv;
  __syncthreads();
  float a1 = 0.f, a2 = 0.f;
#pragma unroll 4
  for (int c = 0; c < 256; ++c) {
    a1 += w1[(size_t)tid * 256 + c] * sl[c];
    a2 += w2[(size_t)tid * 256 + c] * sl[c];
  }
  u1[b * 256 + tid] = a1;
  u2[b * 256 + tid] = a2;
}

// ---------------- k_smallmm: C = A @ B (256^3, batched strides) ------------
__global__ __launch_bounds__(256) void k_smallmm(const float* __restrict__ A, long asb,
                                                 const float* __restrict__ Bm, long bsb,
                                                 float* __restrict__ Cm, long csb) {
  const int b  = blockIdx.y;
  const int i0 = blockIdx.x * 8;
  const float* Ab = A  + (size_t)asb * b;
  const float* Bb = Bm + (size_t)bsb * b;
  float*       Cb = Cm + (size_t)csb * b;
  const int tid = threadIdx.x;
  __shared__ float arows[8][256];
#pragma unroll
  for (int rr = 0; rr < 8; ++rr) arows[rr][tid] = Ab[(size_t)(i0 + rr) * 256 + tid];
  __syncthreads();
  float acc[8] = {};
#pragma unroll 4
  for (int k = 0; k < 256; ++k) {
    const float bv = Bb[(size_t)k * 256 + tid];
#pragma unroll
    for (int rr = 0; rr < 8; ++rr) acc[rr] += arows[rr][k] * bv;
  }
#pragma unroll
  for (int rr = 0; rr < 8; ++rr) Cb[(size_t)(i0 + rr) * 256 + tid] = acc[rr];
}

// ------- k_softmax: logits finish + softmax; store Abf = softmax + I --------
__global__ __launch_bounds__(256) void k_softmax(const float* __restrict__ L,
                                                 const float* __restrict__ b1,
                                                 const float* __restrict__ b2,
                                                 const float* __restrict__ u1,
                                                 const float* __restrict__ u2,
                                                 unsigned short* __restrict__ Abf) {
  const int b = blockIdx.y, i = blockIdx.x, j = threadIdx.x;
  const size_t base = ((size_t)b * 256 + i) * 256;
  const float v = L[base + j] + u1[b * 256 + i] * b2[j] +
                  b1[i] * (u2[b * 256 + j] + 16384.f * b2[j]);
  const int lane = j & 63, wv = j >> 6;
  __shared__ float redm[4], reds[4];
  float m = v;
#pragma unroll
  for (int off = 32; off; off >>= 1) m = fmaxf(m, __shfl_xor(m, off, 64));
  if (lane == 0) redm[wv] = m;
  __syncthreads();
  m = fmaxf(fmaxf(redm[0], redm[1]), fmaxf(redm[2], redm[3]));
  const float e = __expf(v - m);
  float sm = e;
#pragma unroll
  for (int off = 32; off; off >>= 1) sm += __shfl_xor(sm, off, 64);
  if (lane == 0) reds[wv] = sm;
  __syncthreads();
  sm = (reds[0] + reds[1]) + (reds[2] + reds[3]);
  float p = e / sm;
  if (j == i) p += 1.0f;                 // residual folded into diagonal
  Abf[base + j] = f2bf(p);
}

// ---------------- k_av: out = (I+A) @ X  (pure-store epilogue) --------------
// XBF=true: X read as bf16 from xbf (half the HBM bytes). Same structure as
// the proven r8 kernel (40 VGPR, no spill).
template<bool XBF>
__global__ __launch_bounds__(256, 4) void k_av(const unsigned short* __restrict__ Abf,
                                               const float* __restrict__ x,
                                               const unsigned short* __restrict__ xbf,
                                               float* __restrict__ out) {
  const int bid = blockIdx.x;
  const int b = bid & 7;
  const int nbase = (bid >> 3) * 32;
  const unsigned short* Ab = Abf + (size_t)b * 65536;
  float* Ob = out + (size_t)b * C_ * NPIX;

  __shared__ __align__(16) unsigned short Xt[32 * 256];   // [px][d], 16 KB

  const int tid = threadIdx.x;
  const int lane = tid & 63, w = tid >> 6;   // w = ch-block 0..3

  if (XBF) {
    const unsigned short* Xh = xbf + (size_t)b * C_ * NPIX;
    const int pq = (tid & 7) * 4;
    const int dq = (tid >> 3) * 4;
#pragma unroll
    for (int h = 0; h < 2; ++h) {
      const int d = dq + h * 128;
      const unsigned short* xs = Xh + (size_t)d * NPIX + nbase + pq;
      ushort4 r0 = *reinterpret_cast<const ushort4*>(xs);
      ushort4 r1 = *reinterpret_cast<const ushort4*>(xs + NPIX);
      ushort4 r2 = *reinterpret_cast<const ushort4*>(xs + 2 * NPIX);
      ushort4 r3 = *reinterpret_cast<const ushort4*>(xs + 3 * NPIX);
      const ushort4 rr[4] = {r0, r1, r2, r3};
#pragma unroll
      for (int i = 0; i < 4; ++i) {
        const int px = pq + i;
        ushort4 v = make_ushort4(((const unsigned short*)&rr[0])[i],
                                 ((const unsigned short*)&rr[1])[i],
                                 ((const unsigned short*)&rr[2])[i],
                                 ((const unsigned short*)&rr[3])[i]);
        const int idx = (px * 256 + d) ^ (((px ^ (px >> 2)) & 7) << 3);
        *reinterpret_cast<ushort4*>(&Xt[idx]) = v;
      }
    }
  } else {
    const float* Xb = x + (size_t)b * C_ * NPIX;
    const int pq = (tid & 7) * 4;
    const int dq = (tid >> 3) * 4;
#pragma unroll
    for (int h = 0; h < 2; ++h) {
      const int d = dq + h * 128;
      const float* xs = Xb + (size_t)d * NPIX + nbase + pq;
      const float4 r0 = *reinterpret_cast<const float4*>(xs);
      const float4 r1 = *reinterpret_cast<const float4*>(xs + NPIX);
      const float4 r2 = *reinterpret_cast<const float4*>(xs + 2 * NPIX);
      const float4 r3 = *reinterpret_cast<const float4*>(xs + 3 * NPIX);
#pragma unroll
      for (int i = 0; i < 4; ++i) {
        const int px = pq + i;
        ushort4 v = make_ushort4(f2bf(fcomp(r0, i)), f2bf(fcomp(r1, i)),
                                 f2bf(fcomp(r2, i)), f2bf(fcomp(r3, i)));
        const int idx = (px * 256 + d) ^ (((px ^ (px >> 2)) & 7) << 3);
        *reinterpret_cast<ushort4*>(&Xt[idx]) = v;
      }
    }
  }
  __syncthreads();

  const int kboff = (lane >> 4) * 8;
  f32x4 acc[4][2] = {};
  bf16x8 afA[4], afB[4], bq[2];

#define LOADA(kk, af)                                                         \
  _Pragma("unroll")                                                           \
  for (int m = 0; m < 4; ++m)                                                 \
    af[m] = *reinterpret_cast<const bf16x8*>(                                 \
        Ab + (size_t)(w * 64 + m * 16 + (lane & 15)) * 256 + (kk) * 32 + kboff);

#define LOADB(kk)                                                             \
  _Pragma("unroll")                                                           \
  for (int n = 0; n < 2; ++n) {                                               \
    const int px = n * 16 + (lane & 15);                                      \
    bq[n] = *reinterpret_cast<const bf16x8*>(                                 \
        &Xt[(px * 256 + (kk) * 32 + kboff) ^ (((px ^ (px >> 2)) & 7) << 3)]); \
  }

#define MFMA8(af)                                                             \
  _Pragma("unroll")                                                           \
  for (int m = 0; m < 4; ++m)                                                 \
    _Pragma("unroll")                                                         \
    for (int n = 0; n < 2; ++n)                                               \
      acc[m][n] = __builtin_amdgcn_mfma_f32_16x16x32_bf16(bq[n], af[m], acc[m][n], 0, 0, 0);

  LOADA(0, afA)
#pragma unroll
  for (int kk = 0; kk < 8; ++kk) {
    LOADB(kk)
    if (kk < 7) {
      if (kk & 1) { LOADA(kk + 1, afA) } else { LOADA(kk + 1, afB) }
    }
    if (kk & 1) { MFMA8(afB) } else { MFMA8(afA) }
  }
#undef LOADA
#undef LOADB
#undef MFMA8

#pragma unroll
  for (int m = 0; m < 4; ++m) {
    const int ch = w * 64 + m * 16 + (lane & 15);
    float* orow = Ob + (size_t)ch * NPIX + nbase;
#pragma unroll
    for (int n = 0; n < 2; ++n) {
      const int p0 = n * 16 + ((lane >> 4) << 2);
      *reinterpret_cast<float4*>(orow + p0) = *reinterpret_cast<const float4*>(&acc[m][n]);
    }
  }
}

extern "C" void kernel_launch(void* const* d_in, const int* in_sizes, int n_in,
                              void* d_out, int out_size, void* d_ws, size_t ws_size,
                              hipStream_t stream) {
  const float* x  = (const float*)d_in[0];
  const float* w1 = (const float*)d_in[1];
  const float* b1 = (const float*)d_in[2];
  const float* w2 = (const float*)d_in[3];
  const float* b2 = (const float*)d_in[4];
  float* out = (float*)d_out;
  char* ws = (char*)d_ws;

  // P-quadrant partials live in d_out (67 MB of its 134 MB) — consumed by
  // k_reduce_sym before k_av overwrites d_out with the real output.
  float* gpart = out;

  constexpr size_t GS_OFF    = 0;                                   // Gs 2 MB
  constexpr size_t T1_OFF    = GS_OFF  + (size_t)B_ * C_ * C_ * 4;
  constexpr size_t L_OFF     = T1_OFF  + (size_t)B_ * C_ * C_ * 4;
  constexpr size_t W2T_OFF   = L_OFF   + (size_t)B_ * C_ * C_ * 4;
  constexpr size_t SPART_OFF = W2T_OFF + (size_t)C_ * C_ * 4;
  constexpr size_t U1_OFF    = SPART_OFF + (size_t)B_ * KCG * C_ * 4;
  constexpr size_t U2_OFF    = U1_OFF  + (size_t)B_ * C_ * 4;
  constexpr size_t ABF_OFF   = U2_OFF  + (size_t)B_ * C_ * 4;
  constexpr size_t XBF_OFF   = ABF_OFF + (size_t)B_ * C_ * C_ * 2;  // 67 MB
  constexpr size_t XBF_BYTES = (size_t)B_ * C_ * NPIX * 2;

  float* Gs    = (float*)(ws + GS_OFF);
  float* T1    = (float*)(ws + T1_OFF);
  float* Lb    = (float*)(ws + L_OFF);
  float* w2t   = (float*)(ws + W2T_OFF);
  float* spart = (float*)(ws + SPART_OFF);
  float* u1    = (float*)(ws + U1_OFF);
  float* u2    = (float*)(ws + U2_OFF);
  unsigned short* Abf = (unsigned short*)(ws + ABF_OFF);
  unsigned short* Xbf = (unsigned short*)(ws + XBF_OFF);

  const bool xbf_ok = ws_size >= XBF_OFF + XBF_BYTES;

  k_transpose <<<64, 256, 0, stream>>>(w2, w2t);
  if (xbf_ok) k_gram<true> <<<1024, 256, 0, stream>>>(x, gpart, spart, Xbf);
  else        k_gram<false><<<1024, 256, 0, stream>>>(x, gpart, spart, nullptr);
  k_reduce_sym<<<dim3(36, B_), 256, 0, stream>>>(gpart, Gs);
  k_u         <<<B_, 256, 0, stream>>>(w1, w2, spart, u1, u2);
  k_smallmm   <<<dim3(32, B_), 256, 0, stream>>>(w1, 0, Gs, C_ * C_, T1, C_ * C_);
  k_smallmm   <<<dim3(32, B_), 256, 0, stream>>>(T1, C_ * C_, w2t, 0, Lb, C_ * C_);
  k_softmax   <<<dim3(C_, B_), 256, 0, stream>>>(Lb, b1, b2, u1, u2, Abf);
  if (xbf_ok) k_av<true> <<<4096, 256, 0, stream>>>(Abf, x, Xbf, out);
  else        k_av<false><<<4096, 256, 0, stream>>>(Abf, x, nullptr, out);
}

// Round 11
// 220.530 us; speedup vs baseline: 1.6641x; 1.1755x over previous
//
#include <hip/hip_runtime.h>
#include <hip/hip_bf16.h>

// Problem sizes (fixed)
#define B_    8
#define C_    256
#define NPIX  16384           // 128*128
#define BK    64
#define KC4   16              // K-chunks for gram
#define KCH4  (NPIX / KC4)    // 1024 k per block
#define NSTEP4 (KCH4 / BK)    // 16 steps per block

typedef __attribute__((ext_vector_type(8))) short bf16x8;
typedef __attribute__((ext_vector_type(4))) float f32x4;
typedef unsigned int uint_;

__device__ __forceinline__ unsigned short f2bf(float x) {
  unsigned int u = __builtin_bit_cast(unsigned int, x);
  u = (u + 0x7fffu + ((u >> 16) & 1u)) >> 16;   // RTNE
  return (unsigned short)u;
}
__device__ __forceinline__ float fcomp(const float4& v, int i) {
  switch (i) { case 0: return v.x; case 1: return v.y; case 2: return v.z; default: return v.w; }
}

// ------- k_gram: partial Gram (3-pass split-bf16), r4/r6 structure ---------
// The measured-best gram (97us, VGPR 108, 1 block/CU, 128KB dbuf LDS).
// grid 256 = half(2) x b(8) x kc(16). Adds Xbf emission: each half-block
// writes the trunc-bf16 of ITS 128 rows (balanced, coalesced 128B runs).
template<bool XBF>
__global__ __launch_bounds__(512, 2) void k_gram(const float* __restrict__ x,
                                                 float* __restrict__ gpart,
                                                 float* __restrict__ spart,
                                                 unsigned short* __restrict__ xbf) {
  const int bid  = blockIdx.x;
  const int half = bid >> 7;
  const int b    = (bid >> 4) & 7;
  const int kc   = bid & 15;
  const float* X = x + (size_t)b * C_ * NPIX + kc * KCH4;

  __shared__ __align__(16) unsigned short Hi[2][256 * 64];   // 2 x 32 KB
  __shared__ __align__(16) unsigned short Lo[2][256 * 64];   // 2 x 32 KB

  const int tid  = threadIdx.x;
  const int lane = tid & 63;
  const int w    = tid >> 6;
  const int wr   = w >> 2;        // 0..1  (row block of 64 within the 128-half)
  const int wc   = w & 3;         // 0..3  (col block of 64)

  // staging: row = j*32 + srow (j=0..7), cols scol..scol+3.
  const int srow = tid >> 4;          // 0..31
  const int scol = (tid & 15) * 4;    // 0..60
  const float* sp = X + (size_t)srow * NPIX + scol;
  unsigned short* xrow = XBF ?
      (xbf + (size_t)b * C_ * NPIX + (size_t)srow * NPIX + kc * KCH4 + scol) : nullptr;

  float rs[8] = {};
  float4 g[8];

#define GLOAD(ks)                                                             \
  _Pragma("unroll")                                                           \
  for (int j = 0; j < 8; ++j)                                                 \
    g[j] = *reinterpret_cast<const float4*>(sp + (size_t)j * 32 * NPIX + (ks) * BK);

#define STAGE(buf, ksn)                                                       \
  _Pragma("unroll")                                                           \
  for (int j = 0; j < 8; ++j) {                                               \
    const float4 v = g[j];                                                    \
    rs[j] += (v.x + v.y) + (v.z + v.w);                                       \
    const uint_ u0 = __builtin_bit_cast(uint_, v.x);                          \
    const uint_ u1 = __builtin_bit_cast(uint_, v.y);                          \
    const uint_ u2 = __builtin_bit_cast(uint_, v.z);                          \
    const uint_ u3 = __builtin_bit_cast(uint_, v.w);                          \
    uint2 hi, lo;                                                             \
    hi.x = (u0 >> 16) | (u1 & 0xffff0000u);                                   \
    hi.y = (u2 >> 16) | (u3 & 0xffff0000u);                                   \
    const float h0 = __builtin_bit_cast(float, u0 & 0xffff0000u);             \
    const float h1 = __builtin_bit_cast(float, u1 & 0xffff0000u);             \
    const float h2 = __builtin_bit_cast(float, u2 & 0xffff0000u);             \
    const float h3 = __builtin_bit_cast(float, u3 & 0xffff0000u);             \
    const uint_ l0 = __builtin_bit_cast(uint_, v.x - h0);                     \
    const uint_ l1 = __builtin_bit_cast(uint_, v.y - h1);                     \
    const uint_ l2 = __builtin_bit_cast(uint_, v.z - h2);                     \
    const uint_ l3 = __builtin_bit_cast(uint_, v.w - h3);                     \
    lo.x = (l0 >> 16) | (l1 & 0xffff0000u);                                   \
    lo.y = (l2 >> 16) | (l3 & 0xffff0000u);                                   \
    const int row = j * 32 + srow;                                            \
    const int idx = (row * 64 + scol) ^ ((row & 7) << 3);                     \
    *reinterpret_cast<uint2*>(&Hi[buf][idx]) = hi;                            \
    *reinterpret_cast<uint2*>(&Lo[buf][idx]) = lo;                            \
    if (XBF && (j >> 2) == half)                                              \
      *reinterpret_cast<uint2*>(xrow + (size_t)j * 32 * NPIX + (ksn) * BK) = hi; \
  }

  GLOAD(0)
  STAGE(0, 0)
  __syncthreads();

  f32x4 acc[4][4] = {};

  for (int ks = 0; ks < NSTEP4; ++ks) {
    const int cur = ks & 1;
    if (ks + 1 < NSTEP4) GLOAD(ks + 1)
    __builtin_amdgcn_s_setprio(1);
#pragma unroll
    for (int kk = 0; kk < 2; ++kk) {
      const int kb = kk * 32 + (lane >> 4) * 8;
      bf16x8 ahi[4], bhi[4], blo[4];
#pragma unroll
      for (int m = 0; m < 4; ++m) {
        const int row = half * 128 + wr * 64 + m * 16 + (lane & 15);
        ahi[m] = *reinterpret_cast<const bf16x8*>(&Hi[cur][(row * 64 + kb) ^ ((row & 7) << 3)]);
      }
#pragma unroll
      for (int n = 0; n < 4; ++n) {
        const int row = wc * 64 + n * 16 + (lane & 15);
        bhi[n] = *reinterpret_cast<const bf16x8*>(&Hi[cur][(row * 64 + kb) ^ ((row & 7) << 3)]);
      }
#pragma unroll
      for (int m = 0; m < 4; ++m)
#pragma unroll
        for (int n = 0; n < 4; ++n)
          acc[m][n] = __builtin_amdgcn_mfma_f32_16x16x32_bf16(ahi[m], bhi[n], acc[m][n], 0, 0, 0);
#pragma unroll
      for (int n = 0; n < 4; ++n) {
        const int row = wc * 64 + n * 16 + (lane & 15);
        blo[n] = *reinterpret_cast<const bf16x8*>(&Lo[cur][(row * 64 + kb) ^ ((row & 7) << 3)]);
      }
#pragma unroll
      for (int m = 0; m < 4; ++m)
#pragma unroll
        for (int n = 0; n < 4; ++n)
          acc[m][n] = __builtin_amdgcn_mfma_f32_16x16x32_bf16(ahi[m], blo[n], acc[m][n], 0, 0, 0);
#pragma unroll
      for (int m = 0; m < 4; ++m) {
        const int row = half * 128 + wr * 64 + m * 16 + (lane & 15);
        bf16x8 alo = *reinterpret_cast<const bf16x8*>(&Lo[cur][(row * 64 + kb) ^ ((row & 7) << 3)]);
#pragma unroll
        for (int n = 0; n < 4; ++n)
          acc[m][n] = __builtin_amdgcn_mfma_f32_16x16x32_bf16(alo, bhi[n], acc[m][n], 0, 0, 0);
      }
    }
    __builtin_amdgcn_s_setprio(0);
    if (ks + 1 < NSTEP4) STAGE(cur ^ 1, ks + 1)
    __syncthreads();
  }
#undef GLOAD
#undef STAGE

  // rowsum partials: 16 lanes share a row; only half==0 blocks write
#pragma unroll
  for (int j = 0; j < 8; ++j) {
#pragma unroll
    for (int off = 1; off < 16; off <<= 1) rs[j] += __shfl_xor(rs[j], off, 64);
  }
  if (half == 0 && (tid & 15) == 0) {
#pragma unroll
    for (int j = 0; j < 8; ++j)
      spart[((size_t)b * KC4 + kc) * 256 + j * 32 + srow] = rs[j];
  }

  // coalesced partial store: gpart[bid] is a 128x256 f32 block
  float* gp = gpart + (size_t)bid * (128 * 256);
#pragma unroll
  for (int m = 0; m < 4; ++m) {
    const int row0 = wr * 64 + m * 16 + ((lane >> 4) << 2);
#pragma unroll
    for (int n = 0; n < 4; ++n) {
      const int col = wc * 64 + n * 16 + (lane & 15);
#pragma unroll
      for (int j = 0; j < 4; ++j)
        gp[(size_t)(row0 + j) * 256 + col] = acc[m][n][j];
    }
  }
}

// ---------------- k_reduce: G = sum_kc partials (float4, coalesced) ---------
__global__ __launch_bounds__(256) void k_reduce(const float* __restrict__ gpart,
                                                float* __restrict__ G) {
  const int t  = blockIdx.x * 256 + threadIdx.x;
  const int b  = t >> 14;
  const int i  = (t >> 6) & 255;
  const int j4 = (t & 63) * 4;
  const int hb = (i >> 7) * 128 + b * 16;
  const int il = i & 127;
  float4 s = make_float4(0.f, 0.f, 0.f, 0.f);
#pragma unroll
  for (int kc = 0; kc < KC4; ++kc) {
    const float4 v = *reinterpret_cast<const float4*>(
        &gpart[(size_t)(hb + kc) * (128 * 256) + (size_t)il * 256 + j4]);
    s.x += v.x; s.y += v.y; s.z += v.z; s.w += v.w;
  }
  *reinterpret_cast<float4*>(&G[((size_t)b * 256 + i) * 256 + j4]) = s;
}

// ---------------- k_transpose: 256x256 (w2 -> w2t) ----------------
__global__ __launch_bounds__(256) void k_transpose(const float* __restrict__ in,
                                                   float* __restrict__ outp) {
  __shared__ float t[32][33];
  const int bx = blockIdx.x & 7, by = blockIdx.x >> 3;
  const int tx = threadIdx.x & 31, ty = threadIdx.x >> 5;
#pragma unroll
  for (int i = 0; i < 32; i += 8)
    t[ty + i][tx] = in[(size_t)(by * 32 + ty + i) * 256 + bx * 32 + tx];
  __syncthreads();
#pragma unroll
  for (int i = 0; i < 32; i += 8)
    outp[(size_t)(bx * 32 + ty + i) * 256 + by * 32 + tx] = t[tx][ty + i];
}

// ---------------- k_u: s = reduce(spart); u1 = W1 s, u2 = W2 s --------------
__global__ __launch_bounds__(256) void k_u(const float* __restrict__ w1,
                                           const float* __restrict__ w2,
                                           const float* __restrict__ spart,
                                           float* __restrict__ u1,
                                           float* __restrict__ u2) {
  const int b = blockIdx.x;
  const int tid = threadIdx.x;
  __shared__ float sl[256];
  float sv = 0.f;
#pragma unroll
  for (int kc = 0; kc < KC4; ++kc) sv += spart[((size_t)b * KC4 + kc) * 256 + tid];
  sl[tid] = sv;
  __syncthreads();
  float a1 = 0.f, a2 = 0.f;
#pragma unroll 4
  for (int c = 0; c < 256; ++c) {
    a1 += w1[(size_t)tid * 256 + c] * sl[c];
    a2 += w2[(size_t)tid * 256 + c] * sl[c];
  }
  u1[b * 256 + tid] = a1;
  u2[b * 256 + tid] = a2;
}

// ---------------- k_smallmm: C = A @ B (256^3, batched strides) ------------
__global__ __launch_bounds__(256) void k_smallmm(const float* __restrict__ A, long asb,
                                                 const float* __restrict__ Bm, long bsb,
                                                 float* __restrict__ Cm, long csb) {
  const int b  = blockIdx.y;
  const int i0 = blockIdx.x * 8;
  const float* Ab = A  + (size_t)asb * b;
  const float* Bb = Bm + (size_t)bsb * b;
  float*       Cb = Cm + (size_t)csb * b;
  const int tid = threadIdx.x;
  __shared__ float arows[8][256];
#pragma unroll
  for (int rr = 0; rr < 8; ++rr) arows[rr][tid] = Ab[(size_t)(i0 + rr) * 256 + tid];
  __syncthreads();
  float acc[8] = {};
#pragma unroll 4
  for (int k = 0; k < 256; ++k) {
    const float bv = Bb[(size_t)k * 256 + tid];
#pragma unroll
    for (int rr = 0; rr < 8; ++rr) acc[rr] += arows[rr][k] * bv;
  }
#pragma unroll
  for (int rr = 0; rr < 8; ++rr) Cb[(size_t)(i0 + rr) * 256 + tid] = acc[rr];
}

// ------- k_softmax: logits finish + softmax; store Abf = softmax + I --------
__global__ __launch_bounds__(256) void k_softmax(const float* __restrict__ L,
                                                 const float* __restrict__ b1,
                                                 const float* __restrict__ b2,
                                                 const float* __restrict__ u1,
                                                 const float* __restrict__ u2,
                                                 unsigned short* __restrict__ Abf) {
  const int b = blockIdx.y, i = blockIdx.x, j = threadIdx.x;
  const size_t base = ((size_t)b * 256 + i) * 256;
  const float v = L[base + j] + u1[b * 256 + i] * b2[j] +
                  b1[i] * (u2[b * 256 + j] + 16384.f * b2[j]);
  const int lane = j & 63, wv = j >> 6;
  __shared__ float redm[4], reds[4];
  float m = v;
#pragma unroll
  for (int off = 32; off; off >>= 1) m = fmaxf(m, __shfl_xor(m, off, 64));
  if (lane == 0) redm[wv] = m;
  __syncthreads();
  m = fmaxf(fmaxf(redm[0], redm[1]), fmaxf(redm[2], redm[3]));
  const float e = __expf(v - m);
  float sm = e;
#pragma unroll
  for (int off = 32; off; off >>= 1) sm += __shfl_xor(sm, off, 64);
  if (lane == 0) reds[wv] = sm;
  __syncthreads();
  sm = (reds[0] + reds[1]) + (reds[2] + reds[3]);
  float p = e / sm;
  if (j == i) p += 1.0f;                 // residual folded into diagonal
  Abf[base + j] = f2bf(p);
}

// ---------------- k_av: out = (I+A) @ X  (pure-store epilogue) --------------
// XBF=true: X read as bf16 from xbf (half the HBM bytes). Proven r8/r10
// structure: 40 VGPR, no spill, 4096 blocks x 256 thr.
template<bool XBF>
__global__ __launch_bounds__(256, 4) void k_av(const unsigned short* __restrict__ Abf,
                                               const float* __restrict__ x,
                                               const unsigned short* __restrict__ xbf,
                                               float* __restrict__ out) {
  const int bid = blockIdx.x;
  const int b = bid & 7;
  const int nbase = (bid >> 3) * 32;
  const unsigned short* Ab = Abf + (size_t)b * 65536;
  float* Ob = out + (size_t)b * C_ * NPIX;

  __shared__ __align__(16) unsigned short Xt[32 * 256];   // [px][d], 16 KB

  const int tid = threadIdx.x;
  const int lane = tid & 63, w = tid >> 6;   // w = ch-block 0..3

  if (XBF) {
    const unsigned short* Xh = xbf + (size_t)b * C_ * NPIX;
    const int pq = (tid & 7) * 4;
    const int dq = (tid >> 3) * 4;
#pragma unroll
    for (int h = 0; h < 2; ++h) {
      const int d = dq + h * 128;
      const unsigned short* xs = Xh + (size_t)d * NPIX + nbase + pq;
      ushort4 r0 = *reinterpret_cast<const ushort4*>(xs);
      ushort4 r1 = *reinterpret_cast<const ushort4*>(xs + NPIX);
      ushort4 r2 = *reinterpret_cast<const ushort4*>(xs + 2 * NPIX);
      ushort4 r3 = *reinterpret_cast<const ushort4*>(xs + 3 * NPIX);
      const ushort4 rr[4] = {r0, r1, r2, r3};
#pragma unroll
      for (int i = 0; i < 4; ++i) {
        const int px = pq + i;
        ushort4 v = make_ushort4(((const unsigned short*)&rr[0])[i],
                                 ((const unsigned short*)&rr[1])[i],
                                 ((const unsigned short*)&rr[2])[i],
                                 ((const unsigned short*)&rr[3])[i]);
        const int idx = (px * 256 + d) ^ (((px ^ (px >> 2)) & 7) << 3);
        *reinterpret_cast<ushort4*>(&Xt[idx]) = v;
      }
    }
  } else {
    const float* Xb = x + (size_t)b * C_ * NPIX;
    const int pq = (tid & 7) * 4;
    const int dq = (tid >> 3) * 4;
#pragma unroll
    for (int h = 0; h < 2; ++h) {
      const int d = dq + h * 128;
      const float* xs = Xb + (size_t)d * NPIX + nbase + pq;
      const float4 r0 = *reinterpret_cast<const float4*>(xs);
      const float4 r1 = *reinterpret_cast<const float4*>(xs + NPIX);
      const float4 r2 = *reinterpret_cast<const float4*>(xs + 2 * NPIX);
      const float4 r3 = *reinterpret_cast<const float4*>(xs + 3 * NPIX);
#pragma unroll
      for (int i = 0; i < 4; ++i) {
        const int px = pq + i;
        ushort4 v = make_ushort4(f2bf(fcomp(r0, i)), f2bf(fcomp(r1, i)),
                                 f2bf(fcomp(r2, i)), f2bf(fcomp(r3, i)));
        const int idx = (px * 256 + d) ^ (((px ^ (px >> 2)) & 7) << 3);
        *reinterpret_cast<ushort4*>(&Xt[idx]) = v;
      }
    }
  }
  __syncthreads();

  const int kboff = (lane >> 4) * 8;
  f32x4 acc[4][2] = {};
  bf16x8 afA[4], afB[4], bq[2];

#define LOADA(kk, af)                                                         \
  _Pragma("unroll")                                                           \
  for (int m = 0; m < 4; ++m)                                                 \
    af[m] = *reinterpret_cast<const bf16x8*>(                                 \
        Ab + (size_t)(w * 64 + m * 16 + (lane & 15)) * 256 + (kk) * 32 + kboff);

#define LOADB(kk)                                                             \
  _Pragma("unroll")                                                           \
  for (int n = 0; n < 2; ++n) {                                               \
    const int px = n * 16 + (lane & 15);                                      \
    bq[n] = *reinterpret_cast<const bf16x8*>(                                 \
        &Xt[(px * 256 + (kk) * 32 + kboff) ^ (((px ^ (px >> 2)) & 7) << 3)]); \
  }

#define MFMA8(af)                                                             \
  _Pragma("unroll")                                                           \
  for (int m = 0; m < 4; ++m)                                                 \
    _Pragma("unroll")                                                         \
    for (int n = 0; n < 2; ++n)                                               \
      acc[m][n] = __builtin_amdgcn_mfma_f32_16x16x32_bf16(bq[n], af[m], acc[m][n], 0, 0, 0);

  LOADA(0, afA)
#pragma unroll
  for (int kk = 0; kk < 8; ++kk) {
    LOADB(kk)
    if (kk < 7) {
      if (kk & 1) { LOADA(kk + 1, afA) } else { LOADA(kk + 1, afB) }
    }
    if (kk & 1) { MFMA8(afB) } else { MFMA8(afA) }
  }
#undef LOADA
#undef LOADB
#undef MFMA8

#pragma unroll
  for (int m = 0; m < 4; ++m) {
    const int ch = w * 64 + m * 16 + (lane & 15);
    float* orow = Ob + (size_t)ch * NPIX + nbase;
#pragma unroll
    for (int n = 0; n < 2; ++n) {
      const int p0 = n * 16 + ((lane >> 4) << 2);
      *reinterpret_cast<float4*>(orow + p0) = *reinterpret_cast<const float4*>(&acc[m][n]);
    }
  }
}

extern "C" void kernel_launch(void* const* d_in, const int* in_sizes, int n_in,
                              void* d_out, int out_size, void* d_ws, size_t ws_size,
                              hipStream_t stream) {
  const float* x  = (const float*)d_in[0];
  const float* w1 = (const float*)d_in[1];
  const float* b1 = (const float*)d_in[2];
  const float* w2 = (const float*)d_in[3];
  const float* b2 = (const float*)d_in[4];
  float* out = (float*)d_out;
  char* ws = (char*)d_ws;

  // Gram partials live in d_out (33.5 MB of its 134 MB) — consumed by
  // k_reduce before k_av overwrites d_out with the real output.
  float* gpart = out;

  constexpr size_t G_OFF     = 0;                                   // 2 MB
  constexpr size_t T1_OFF    = G_OFF   + (size_t)B_ * C_ * C_ * 4;  // 2 MB
  constexpr size_t L_OFF     = T1_OFF  + (size_t)B_ * C_ * C_ * 4;  // 2 MB
  constexpr size_t W2T_OFF   = L_OFF   + (size_t)B_ * C_ * C_ * 4;  // 256 KB
  constexpr size_t SPART_OFF = W2T_OFF + (size_t)C_ * C_ * 4;       // 128 KB
  constexpr size_t U1_OFF    = SPART_OFF + (size_t)B_ * KC4 * C_ * 4;
  constexpr size_t U2_OFF    = U1_OFF  + (size_t)B_ * C_ * 4;
  constexpr size_t ABF_OFF   = U2_OFF  + (size_t)B_ * C_ * 4;       // 1 MB
  constexpr size_t XBF_OFF   = ABF_OFF + (size_t)B_ * C_ * C_ * 2;  // 67 MB
  constexpr size_t XBF_BYTES = (size_t)B_ * C_ * NPIX * 2;

  float* G     = (float*)(ws + G_OFF);
  float* T1    = (float*)(ws + T1_OFF);
  float* Lb    = (float*)(ws + L_OFF);
  float* w2t   = (float*)(ws + W2T_OFF);
  float* spart = (float*)(ws + SPART_OFF);
  float* u1    = (float*)(ws + U1_OFF);
  float* u2    = (float*)(ws + U2_OFF);
  unsigned short* Abf = (unsigned short*)(ws + ABF_OFF);
  unsigned short* Xbf = (unsigned short*)(ws + XBF_OFF);

  const bool xbf_ok = ws_size >= XBF_OFF + XBF_BYTES;

  k_transpose<<<64, 256, 0, stream>>>(w2, w2t);
  if (xbf_ok) k_gram<true> <<<256, 512, 0, stream>>>(x, gpart, spart, Xbf);
  else        k_gram<false><<<256, 512, 0, stream>>>(x, gpart, spart, nullptr);
  k_reduce   <<<512, 256, 0, stream>>>(gpart, G);
  k_u        <<<B_, 256, 0, stream>>>(w1, w2, spart, u1, u2);
  k_smallmm  <<<dim3(32, B_), 256, 0, stream>>>(w1, 0, G, C_ * C_, T1, C_ * C_);
  k_smallmm  <<<dim3(32, B_), 256, 0, stream>>>(T1, C_ * C_, w2t, 0, Lb, C_ * C_);
  k_softmax  <<<dim3(C_, B_), 256, 0, stream>>>(Lb, b1, b2, u1, u2, Abf);
  if (xbf_ok) k_av<true> <<<4096, 256, 0, stream>>>(Abf, x, Xbf, out);
  else        k_av<false><<<4096, 256, 0, stream>>>(Abf, x, nullptr, out);
}